// Round 12
// baseline (335.322 us; speedup 1.0000x reference)
//
#include <hip/hip_runtime.h>
#include <stdint.h>

#define NN 50000
#define NE 800000
#define GG 782     // gemm grid: (NN + 63) / 64
#define NB 196     // scan blocks: (NN + 255) / 256
#define EB 3125    // edge blocks: NE / 256
#define LDSROW 136 // padded LDS row stride (bf16 elems): 272 B -> 2-way bank conflicts only

typedef __attribute__((ext_vector_type(8))) short bfx8;   // 8 bf16 (4 VGPRs)
typedef __attribute__((ext_vector_type(4))) float f32x4;  // MFMA acc

// ---- bf16 helpers (RNE) ----
__device__ inline unsigned short f2bf(float f) {
    union { float f; uint32_t u; } x; x.f = f;
    uint32_t u = x.u;
    return (unsigned short)((u + 0x7fffu + ((u >> 16) & 1u)) >> 16);
}
__device__ inline uint32_t pack2bf(float lo, float hi) {
    return (uint32_t)f2bf(lo) | ((uint32_t)f2bf(hi) << 16);
}
__device__ inline float bf2f(unsigned short h) {
    union { uint32_t u; float f; } c; c.u = ((uint32_t)h) << 16;
    return c.f;
}
__device__ inline float2 bfp2f2(uint32_t v) {
    union { uint32_t u; float f; } a, b;
    a.u = (v & 0xffffu) << 16;
    b.u = v & 0xffff0000u;
    return make_float2(a.f, b.f);
}
__device__ inline bfx8 ld8(const unsigned short* p) {
    union { uint4 u; bfx8 v; } c;
    c.u = *(const uint4*)p;
    return c.v;
}
__device__ inline bfx8 ld8_lds(const unsigned short* p) {
    union { uint4 u; bfx8 v; } c;
    c.u = *(const uint4*)p;
    return c.v;
}
__device__ inline bfx8 cvt8(float4 u, float4 v) {
    union { unsigned short s[8]; bfx8 r; } c;
    c.s[0] = f2bf(u.x); c.s[1] = f2bf(u.y); c.s[2] = f2bf(u.z); c.s[3] = f2bf(u.w);
    c.s[4] = f2bf(v.x); c.s[5] = f2bf(v.y); c.s[6] = f2bf(v.z); c.s[7] = f2bf(v.w);
    return c.r;
}

// ---------- D1: W transposes | zero hist ----------
__global__ void prep(const float* __restrict__ W1, const float* __restrict__ W2,
                     const float* __restrict__ W3,
                     unsigned short* __restrict__ WT1, unsigned short* __restrict__ WT2,
                     unsigned short* __restrict__ WT3, int* __restrict__ hist) {
    int bid = blockIdx.x;
    if (bid < 152) {
        int w = bid * 256 + threadIdx.x;
        if (w < 16384) {
            int nn = w >> 7, k = w & 127;
            WT1[nn * 128 + k] = f2bf(W1[k * 128 + nn]);
        } else if (w < 32768) {
            int w2 = w - 16384, nn = w2 >> 7, k = w2 & 127;
            WT2[nn * 128 + k] = f2bf(W2[k * 128 + nn]);
        } else if (w < 38912) {
            int w2 = w - 32768, nn = w2 >> 7, k = w2 & 127;  // 48x128, zero-pad
            WT3[nn * 128 + k] = (nn < 40) ? f2bf(W3[k * 40 + nn]) : (unsigned short)0;
        }
    } else {
        int i = (bid - 152) * 256 + threadIdx.x;
        if (i < NN) hist[i] = 0;
    }
}

// ---------- D2: layer-1 GEMM (fp32 X, UNSCALED H1) ∪ hist_rank ----------
__global__ __launch_bounds__(256) void gemm1_hist(const float* __restrict__ X,
                                                  const unsigned short* __restrict__ WT,
                                                  unsigned short* __restrict__ G, int n,
                                                  const int* __restrict__ dst,
                                                  int* __restrict__ hist,
                                                  unsigned short* __restrict__ rank, int e) {
    if (blockIdx.x >= GG) {
        int i = (blockIdx.x - GG) * 256 + threadIdx.x;
        if (i < e) rank[i] = (unsigned short)atomicAdd(hist + dst[i], 1);
        return;
    }
    int wave = threadIdx.x >> 6;
    int lane = threadIdx.x & 63;
    int quad = lane >> 4;
    int c = lane & 15;
    int rowbase = blockIdx.x * 64 + wave * 16;

    int arow = rowbase + c;
    if (arow >= n) arow = n - 1;
    const float* ap = X + (size_t)arow * 128 + quad * 8;
    bfx8 a[4];
#pragma unroll
    for (int kc = 0; kc < 4; kc++) {
        float4 u = *(const float4*)(ap + kc * 32);
        float4 v = *(const float4*)(ap + kc * 32 + 4);
        a[kc] = cvt8(u, v);
    }

    f32x4 acc[8];
#pragma unroll
    for (int ct = 0; ct < 8; ct++) acc[ct] = (f32x4){0.f, 0.f, 0.f, 0.f};
#pragma unroll
    for (int ct = 0; ct < 8; ct++) {
        const unsigned short* bp = WT + (size_t)(ct * 16 + c) * 128 + quad * 8;
#pragma unroll
        for (int kc = 0; kc < 4; kc++) {
            bfx8 b = ld8(bp + kc * 32);
            acc[ct] = __builtin_amdgcn_mfma_f32_16x16x32_bf16(a[kc], b, acc[ct], 0, 0, 0);
        }
    }

    int r0 = rowbase + quad * 4;
    bool odd = lane & 1;
#pragma unroll
    for (int ct = 0; ct < 8; ct++) {
        float x0 = acc[ct][0], x1 = acc[ct][1], x2 = acc[ct][2], x3 = acc[ct][3];
        float y0 = __shfl_xor(x0, 1, 64), y1 = __shfl_xor(x1, 1, 64);
        float y2 = __shfl_xor(x2, 1, 64), y3 = __shfl_xor(x3, 1, 64);
        int colp = ct * 16 + (c & ~1);
        if (!odd) {
            if (r0 + 0 < n) *(uint32_t*)(&G[(size_t)(r0 + 0) * 128 + colp]) = pack2bf(x0, y0);
            if (r0 + 1 < n) *(uint32_t*)(&G[(size_t)(r0 + 1) * 128 + colp]) = pack2bf(x1, y1);
        } else {
            if (r0 + 2 < n) *(uint32_t*)(&G[(size_t)(r0 + 2) * 128 + colp]) = pack2bf(y2, x2);
            if (r0 + 3 < n) *(uint32_t*)(&G[(size_t)(r0 + 3) * 128 + colp]) = pack2bf(y3, x3);
        }
    }
}

// ---------- D3: scan1 pieces + bsum + dinv ----------
__global__ void scan_dinv(const int* __restrict__ hist, int* row_ptr, int* bsum,
                          float* dinv, int n) {
    __shared__ int s[256];
    int tid = threadIdx.x;
    int i = blockIdx.x * 256 + tid;
    int v = (i < n) ? hist[i] : 0;
    s[tid] = v;
    __syncthreads();
#pragma unroll
    for (int off = 1; off < 256; off <<= 1) {
        int y = (tid >= off) ? s[tid - off] : 0;
        __syncthreads();
        s[tid] += y;
        __syncthreads();
    }
    if (i < n) {
        row_ptr[i] = s[tid] - v;
        dinv[i] = rsqrtf(1.0f + (float)v);
    }
    if (tid == 255) bsum[blockIdx.x] = s[255];
}

// ---------- D4: bucket with inline LDS scan2; last block publishes boff ----------
__global__ void bucket_k(const int* __restrict__ src, const int* __restrict__ dst,
                         const int* __restrict__ row_ptr, const int* __restrict__ bsum,
                         const unsigned short* __restrict__ rank,
                         unsigned short* __restrict__ csr_src, int* __restrict__ boff_g,
                         int e) {
    __shared__ int s[256];
    __shared__ int bex[256];
    int tid = threadIdx.x;
    int v = (tid < NB) ? bsum[tid] : 0;
    s[tid] = v;
    __syncthreads();
#pragma unroll
    for (int off = 1; off < 256; off <<= 1) {
        int y = (tid >= off) ? s[tid - off] : 0;
        __syncthreads();
        s[tid] += y;
        __syncthreads();
    }
    bex[tid] = s[tid] - v;
    __syncthreads();

    if (blockIdx.x == gridDim.x - 1) {
        if (tid < NB) boff_g[tid] = bex[tid];
        return;
    }
    int i = blockIdx.x * 256 + tid;
    if (i < e) {
        int d = dst[i];
        csr_src[row_ptr[d] + bex[d >> 8] + (int)rank[i]] = (unsigned short)src[i];
    }
}

// ---------- D5: fused [aggregate layer-1 (per-edge dinv) -> GEMM(WT2)] ----------
// Wave-local: each wave aggregates its 16 nodes into its private LDS tile
// (stride 136 -> 2-way LDS conflicts only), then MFMAs the tile. No barriers.
__global__ __launch_bounds__(256) void agg1_gemm2(const unsigned short* __restrict__ G,
                                                  const int* __restrict__ row_ptr,
                                                  const int* __restrict__ boff,
                                                  const int* __restrict__ hist,
                                                  const unsigned short* __restrict__ csr_src,
                                                  const float* __restrict__ dinv,
                                                  const float* __restrict__ b,
                                                  const unsigned short* __restrict__ WT,
                                                  unsigned short* __restrict__ Gout, int n) {
    __shared__ unsigned short As[4 * 16 * LDSROW];  // 17408 B
    int wave = threadIdx.x >> 6;
    int lane = threadIdx.x & 63;
    int rowbase = blockIdx.x * 64 + wave * 16;
    unsigned short* myA = As + wave * 16 * LDSROW;
    const uint32_t* Gr = (const uint32_t*)G;
    int l = lane;

    // Phase A: aggregate 16 nodes (one per iteration; 64 lanes = 2 features each)
    for (int i = 0; i < 16; i++) {
        int node = rowbase + i;
        uint32_t* wp = (uint32_t*)(myA + i * LDSROW);
        if (node >= n) { wp[l] = 0; continue; }
        float dn = dinv[node];
        float2 sf = bfp2f2(Gr[(size_t)node * 64 + l]);
        float2 acc = make_float2(dn * sf.x, dn * sf.y);  // self: dinv[d]*H1[d]
        int p = row_ptr[node] + boff[node >> 8];
        int p1 = p + hist[node];
        for (; p + 7 < p1; p += 8) {
            int s0 = csr_src[p],     s1 = csr_src[p + 1], s2 = csr_src[p + 2], s3 = csr_src[p + 3];
            int s4 = csr_src[p + 4], s5 = csr_src[p + 5], s6 = csr_src[p + 6], s7 = csr_src[p + 7];
            float d0 = dinv[s0], d1 = dinv[s1], d2 = dinv[s2], d3 = dinv[s3];
            float d4 = dinv[s4], d5 = dinv[s5], d6 = dinv[s6], d7 = dinv[s7];
            float2 f0 = bfp2f2(Gr[(size_t)s0 * 64 + l]), f1 = bfp2f2(Gr[(size_t)s1 * 64 + l]);
            float2 f2 = bfp2f2(Gr[(size_t)s2 * 64 + l]), f3 = bfp2f2(Gr[(size_t)s3 * 64 + l]);
            float2 f4 = bfp2f2(Gr[(size_t)s4 * 64 + l]), f5 = bfp2f2(Gr[(size_t)s5 * 64 + l]);
            float2 f6 = bfp2f2(Gr[(size_t)s6 * 64 + l]), f7 = bfp2f2(Gr[(size_t)s7 * 64 + l]);
            acc.x += (fmaf(d0, f0.x, d1 * f1.x) + fmaf(d2, f2.x, d3 * f3.x)) +
                     (fmaf(d4, f4.x, d5 * f5.x) + fmaf(d6, f6.x, d7 * f7.x));
            acc.y += (fmaf(d0, f0.y, d1 * f1.y) + fmaf(d2, f2.y, d3 * f3.y)) +
                     (fmaf(d4, f4.y, d5 * f5.y) + fmaf(d6, f6.y, d7 * f7.y));
        }
        for (; p < p1; ++p) {
            int s = csr_src[p];
            float ds = dinv[s];
            float2 f = bfp2f2(Gr[(size_t)s * 64 + l]);
            acc.x = fmaf(ds, f.x, acc.x);
            acc.y = fmaf(ds, f.y, acc.y);
        }
        float vx = fmaf(dn, acc.x, b[2 * l]);
        float vy = fmaf(dn, acc.y, b[2 * l + 1]);
        wp[l] = pack2bf(vx > 0.f ? vx : 0.f, vy > 0.f ? vy : 0.f);  // relu'd A-row
    }

    // Phase B: MFMA the wave's 16x128 LDS tile against WT (8 col-tiles)
    int quad = lane >> 4;
    int c = lane & 15;
    bfx8 a[4];
#pragma unroll
    for (int kc = 0; kc < 4; kc++)
        a[kc] = ld8_lds(myA + c * LDSROW + quad * 8 + kc * 32);

    f32x4 acc[8];
#pragma unroll
    for (int ct = 0; ct < 8; ct++) acc[ct] = (f32x4){0.f, 0.f, 0.f, 0.f};
#pragma unroll
    for (int ct = 0; ct < 8; ct++) {
        const unsigned short* bp = WT + (size_t)(ct * 16 + c) * 128 + quad * 8;
#pragma unroll
        for (int kc = 0; kc < 4; kc++) {
            bfx8 bb = ld8(bp + kc * 32);
            acc[ct] = __builtin_amdgcn_mfma_f32_16x16x32_bf16(a[kc], bb, acc[ct], 0, 0, 0);
        }
    }

    int r0 = rowbase + quad * 4;
    float di[4];
#pragma unroll
    for (int r = 0; r < 4; r++) {
        int rr = r0 + r;
        di[r] = dinv[rr < n ? rr : 0];
    }
    bool odd = lane & 1;
#pragma unroll
    for (int ct = 0; ct < 8; ct++) {
        float x0 = acc[ct][0], x1 = acc[ct][1], x2 = acc[ct][2], x3 = acc[ct][3];
        float y0 = __shfl_xor(x0, 1, 64), y1 = __shfl_xor(x1, 1, 64);
        float y2 = __shfl_xor(x2, 1, 64), y3 = __shfl_xor(x3, 1, 64);
        int colp = ct * 16 + (c & ~1);
        if (!odd) {
            if (r0 + 0 < n) *(uint32_t*)(&Gout[(size_t)(r0 + 0) * 128 + colp]) = pack2bf(di[0] * x0, di[0] * y0);
            if (r0 + 1 < n) *(uint32_t*)(&Gout[(size_t)(r0 + 1) * 128 + colp]) = pack2bf(di[1] * x1, di[1] * y1);
        } else {
            if (r0 + 2 < n) *(uint32_t*)(&Gout[(size_t)(r0 + 2) * 128 + colp]) = pack2bf(di[2] * y2, di[2] * x2);
            if (r0 + 3 < n) *(uint32_t*)(&Gout[(size_t)(r0 + 3) * 128 + colp]) = pack2bf(di[3] * y3, di[3] * x3);
        }
    }
}

// ---------- D6: fused [aggregate layer-2 (pre-scaled) -> GEMM40(WT3)] ----------
__global__ __launch_bounds__(256) void agg2_gemm3(const unsigned short* __restrict__ G,
                                                  const int* __restrict__ row_ptr,
                                                  const int* __restrict__ boff,
                                                  const int* __restrict__ hist,
                                                  const unsigned short* __restrict__ csr_src,
                                                  const float* __restrict__ dinv,
                                                  const float* __restrict__ b,
                                                  const unsigned short* __restrict__ WT,
                                                  unsigned short* __restrict__ Gout, int n) {
    __shared__ unsigned short As[4 * 16 * LDSROW];
    int wave = threadIdx.x >> 6;
    int lane = threadIdx.x & 63;
    int rowbase = blockIdx.x * 64 + wave * 16;
    unsigned short* myA = As + wave * 16 * LDSROW;
    const uint32_t* Gr = (const uint32_t*)G;
    int l = lane;

    for (int i = 0; i < 16; i++) {
        int node = rowbase + i;
        uint32_t* wp = (uint32_t*)(myA + i * LDSROW);
        if (node >= n) { wp[l] = 0; continue; }
        float2 acc = bfp2f2(Gr[(size_t)node * 64 + l]);  // self (pre-scaled)
        int p = row_ptr[node] + boff[node >> 8];
        int p1 = p + hist[node];
        for (; p + 7 < p1; p += 8) {
            int s0 = csr_src[p],     s1 = csr_src[p + 1], s2 = csr_src[p + 2], s3 = csr_src[p + 3];
            int s4 = csr_src[p + 4], s5 = csr_src[p + 5], s6 = csr_src[p + 6], s7 = csr_src[p + 7];
            float2 f0 = bfp2f2(Gr[(size_t)s0 * 64 + l]), f1 = bfp2f2(Gr[(size_t)s1 * 64 + l]);
            float2 f2 = bfp2f2(Gr[(size_t)s2 * 64 + l]), f3 = bfp2f2(Gr[(size_t)s3 * 64 + l]);
            float2 f4 = bfp2f2(Gr[(size_t)s4 * 64 + l]), f5 = bfp2f2(Gr[(size_t)s5 * 64 + l]);
            float2 f6 = bfp2f2(Gr[(size_t)s6 * 64 + l]), f7 = bfp2f2(Gr[(size_t)s7 * 64 + l]);
            acc.x += ((f0.x + f1.x) + (f2.x + f3.x)) + ((f4.x + f5.x) + (f6.x + f7.x));
            acc.y += ((f0.y + f1.y) + (f2.y + f3.y)) + ((f4.y + f5.y) + (f6.y + f7.y));
        }
        for (; p < p1; ++p) {
            float2 f = bfp2f2(Gr[(size_t)csr_src[p] * 64 + l]);
            acc.x += f.x; acc.y += f.y;
        }
        float dn = dinv[node];
        float vx = fmaf(dn, acc.x, b[2 * l]);
        float vy = fmaf(dn, acc.y, b[2 * l + 1]);
        wp[l] = pack2bf(vx > 0.f ? vx : 0.f, vy > 0.f ? vy : 0.f);
    }

    int quad = lane >> 4;
    int c = lane & 15;
    bfx8 a[4];
#pragma unroll
    for (int kc = 0; kc < 4; kc++)
        a[kc] = ld8_lds(myA + c * LDSROW + quad * 8 + kc * 32);

    f32x4 acc[3];
#pragma unroll
    for (int ct = 0; ct < 3; ct++) acc[ct] = (f32x4){0.f, 0.f, 0.f, 0.f};
#pragma unroll
    for (int ct = 0; ct < 3; ct++) {
        const unsigned short* bp = WT + (size_t)(ct * 16 + c) * 128 + quad * 8;
#pragma unroll
        for (int kc = 0; kc < 4; kc++) {
            bfx8 bb = ld8(bp + kc * 32);
            acc[ct] = __builtin_amdgcn_mfma_f32_16x16x32_bf16(a[kc], bb, acc[ct], 0, 0, 0);
        }
    }

    int r0 = rowbase + quad * 4;
    float di[4];
#pragma unroll
    for (int r = 0; r < 4; r++) {
        int rr = r0 + r;
        di[r] = dinv[rr < n ? rr : 0];
    }
    bool odd = lane & 1;
#pragma unroll
    for (int ct = 0; ct < 3; ct++) {
        float x0 = acc[ct][0], x1 = acc[ct][1], x2 = acc[ct][2], x3 = acc[ct][3];
        float y0 = __shfl_xor(x0, 1, 64), y1 = __shfl_xor(x1, 1, 64);
        float y2 = __shfl_xor(x2, 1, 64), y3 = __shfl_xor(x3, 1, 64);
        int colp = ct * 16 + (c & ~1);
        if (colp >= 40) continue;
        if (!odd) {
            if (r0 + 0 < n) *(uint32_t*)(&Gout[(size_t)(r0 + 0) * 40 + colp]) = pack2bf(di[0] * x0, di[0] * y0);
            if (r0 + 1 < n) *(uint32_t*)(&Gout[(size_t)(r0 + 1) * 40 + colp]) = pack2bf(di[1] * x1, di[1] * y1);
        } else {
            if (r0 + 2 < n) *(uint32_t*)(&Gout[(size_t)(r0 + 2) * 40 + colp]) = pack2bf(di[2] * y2, di[2] * x2);
            if (r0 + 3 < n) *(uint32_t*)(&Gout[(size_t)(r0 + 3) * 40 + colp]) = pack2bf(di[3] * y3, di[3] * x3);
        }
    }
}

// ---------- D7: 40-wide aggregate + log_softmax ----------
__global__ __launch_bounds__(256) void agg40_lsm(const unsigned short* __restrict__ G,
                                                 const int* __restrict__ row_ptr,
                                                 const int* __restrict__ boff,
                                                 const int* __restrict__ hist,
                                                 const unsigned short* __restrict__ csr_src,
                                                 const float* __restrict__ dinv,
                                                 const float* __restrict__ b,
                                                 float* __restrict__ Y, int n) {
    int node = blockIdx.x * 4 + (threadIdx.x >> 6);
    if (node >= n) return;
    int lane = threadIdx.x & 63;
    bool act = lane < 40;
    int lc = act ? lane : 0;

    float acc = act ? bf2f(G[(size_t)node * 40 + lane]) : 0.f;
    int p = row_ptr[node] + boff[node >> 8];
    int p1 = p + hist[node];
    for (; p + 3 < p1; p += 4) {
        int s0 = csr_src[p], s1 = csr_src[p + 1], s2 = csr_src[p + 2], s3 = csr_src[p + 3];
        float f0 = bf2f(G[(size_t)s0 * 40 + lc]);
        float f1 = bf2f(G[(size_t)s1 * 40 + lc]);
        float f2 = bf2f(G[(size_t)s2 * 40 + lc]);
        float f3 = bf2f(G[(size_t)s3 * 40 + lc]);
        acc += (f0 + f1) + (f2 + f3);
    }
    for (; p < p1; ++p) acc += bf2f(G[(size_t)csr_src[p] * 40 + lc]);

    float v = act ? fmaf(dinv[node], acc, b[lane]) : -1e30f;
    float m = v;
#pragma unroll
    for (int off = 32; off > 0; off >>= 1) m = fmaxf(m, __shfl_xor(m, off, 64));
    float ex = act ? expf(v - m) : 0.f;
    float s_ = ex;
#pragma unroll
    for (int off = 32; off > 0; off >>= 1) s_ += __shfl_xor(s_, off, 64);
    float ls = logf(s_);
    if (act) Y[(size_t)node * 40 + lane] = v - m - ls;
}

// ---------- launch ----------

extern "C" void kernel_launch(void* const* d_in, const int* in_sizes, int n_in,
                              void* d_out, int out_size, void* d_ws, size_t ws_size,
                              hipStream_t stream) {
    const float* x  = (const float*)d_in[0];
    const int*   ei = (const int*)d_in[1];
    const float* W1 = (const float*)d_in[2];
    const float* b1 = (const float*)d_in[3];
    const float* W2 = (const float*)d_in[4];
    const float* b2 = (const float*)d_in[5];
    const float* W3 = (const float*)d_in[6];
    const float* b3 = (const float*)d_in[7];
    float* out = (float*)d_out;

    const int n = NN, e = NE;
    const int* srcI = ei;
    const int* dstI = ei + e;

    char* ws = (char*)d_ws;
    int*            hist    = (int*)ws;                          // n ints
    int*            row_ptr = (int*)(ws + 200704);               // n ints
    int*            bsum    = (int*)(ws + 401408);               // 256
    int*            boff    = (int*)(ws + 402432);               // 256
    float*          dinv    = (float*)(ws + 403456);             // n fp32
    unsigned short* rank    = (unsigned short*)(ws + 604160);    // E ushort
    unsigned short* csr_src = (unsigned short*)(ws + 2204160);   // E ushort
    unsigned short* WT1     = (unsigned short*)(ws + 3804160);   // 128x128 bf16
    unsigned short* WT2     = (unsigned short*)(ws + 3836928);
    unsigned short* WT3     = (unsigned short*)(ws + 3869696);   // 48x128 bf16
    unsigned short* bufG    = (unsigned short*)(ws + 3881984);   // n*128 bf16 (G1)
    unsigned short* bufB    = (unsigned short*)(ws + 16681984);  // n*128 bf16 (G2)
    unsigned short* G40     = bufG;                              // reuse after D5

    // D1: W transposes + zero hist
    prep<<<152 + NB, 256, 0, stream>>>(W1, W2, W3, WT1, WT2, WT3, hist);
    // D2: layer-1 GEMM (unscaled H1) ∪ histogram+ranks
    gemm1_hist<<<GG + EB, 256, 0, stream>>>(x, WT1, bufG, n, dstI, hist, rank, e);
    // D3: scan pieces + dinv
    scan_dinv<<<NB, 256, 0, stream>>>(hist, row_ptr, bsum, dinv, n);
    // D4: bucket (inline scan2) + boff publish
    bucket_k<<<EB + 1, 256, 0, stream>>>(srcI, dstI, row_ptr, bsum, rank, csr_src, boff, e);
    // D5: fused agg-L1 + GEMM(WT2) -> pre-scaled G2
    agg1_gemm2<<<GG, 256, 0, stream>>>(bufG, row_ptr, boff, hist, csr_src, dinv, b1, WT2, bufB, n);
    // D6: fused agg-L2 + GEMM40(WT3) -> pre-scaled G40
    agg2_gemm3<<<GG, 256, 0, stream>>>(bufB, row_ptr, boff, hist, csr_src, dinv, b2, WT3, G40, n);
    // D7: aggregate + log_softmax -> out
    agg40_lsm<<<(n + 3) / 4, 256, 0, stream>>>(G40, row_ptr, boff, hist, csr_src, dinv, b3, out, n);
}

// Round 13
// 295.020 us; speedup vs baseline: 1.1366x; 1.1366x over previous
//
#include <hip/hip_runtime.h>
#include <stdint.h>

#define NN 50000
#define NE 800000
#define GG 782     // gemm grid: (NN + 63) / 64
#define NB 196     // scan blocks: (NN + 255) / 256
#define EB 3125    // edge blocks: NE / 256

typedef __attribute__((ext_vector_type(8))) short bfx8;   // 8 bf16 (4 VGPRs)
typedef __attribute__((ext_vector_type(4))) float f32x4;  // MFMA acc

// ---- bf16 helpers (RNE) ----
__device__ inline unsigned short f2bf(float f) {
    union { float f; uint32_t u; } x; x.f = f;
    uint32_t u = x.u;
    return (unsigned short)((u + 0x7fffu + ((u >> 16) & 1u)) >> 16);
}
__device__ inline uint32_t pack2bf(float lo, float hi) {
    return (uint32_t)f2bf(lo) | ((uint32_t)f2bf(hi) << 16);
}
__device__ inline float bf2f(unsigned short h) {
    union { uint32_t u; float f; } c; c.u = ((uint32_t)h) << 16;
    return c.f;
}
__device__ inline float2 bfp2f2(uint32_t v) {
    union { uint32_t u; float f; } a, b;
    a.u = (v & 0xffffu) << 16;
    b.u = v & 0xffff0000u;
    return make_float2(a.f, b.f);
}
__device__ inline bfx8 ld8(const unsigned short* p) {
    union { uint4 u; bfx8 v; } c;
    c.u = *(const uint4*)p;
    return c.v;
}
__device__ inline bfx8 cvt8(float4 u, float4 v) {
    union { unsigned short s[8]; bfx8 r; } c;
    c.s[0] = f2bf(u.x); c.s[1] = f2bf(u.y); c.s[2] = f2bf(u.z); c.s[3] = f2bf(u.w);
    c.s[4] = f2bf(v.x); c.s[5] = f2bf(v.y); c.s[6] = f2bf(v.z); c.s[7] = f2bf(v.w);
    return c.r;
}

// ---------- D1: W transposes | zero hist ----------
__global__ void prep(const float* __restrict__ W1, const float* __restrict__ W2,
                     const float* __restrict__ W3,
                     unsigned short* __restrict__ WT1, unsigned short* __restrict__ WT2,
                     unsigned short* __restrict__ WT3, int* __restrict__ hist) {
    int bid = blockIdx.x;
    if (bid < 152) {
        int w = bid * 256 + threadIdx.x;
        if (w < 16384) {
            int nn = w >> 7, k = w & 127;
            WT1[nn * 128 + k] = f2bf(W1[k * 128 + nn]);
        } else if (w < 32768) {
            int w2 = w - 16384, nn = w2 >> 7, k = w2 & 127;
            WT2[nn * 128 + k] = f2bf(W2[k * 128 + nn]);
        } else if (w < 38912) {
            int w2 = w - 32768, nn = w2 >> 7, k = w2 & 127;  // 48x128, zero-pad
            WT3[nn * 128 + k] = (nn < 40) ? f2bf(W3[k * 40 + nn]) : (unsigned short)0;
        }
    } else {
        int i = (bid - 152) * 256 + threadIdx.x;
        if (i < NN) hist[i] = 0;
    }
}

// ---------- D2: layer-1 GEMM (fp32 X, UNSCALED H1) ∪ hist_rank ----------
// gemm1 (~14 us) hides fully under the returning-atomic pass (~48 us) — m114-style
// MFMA/atomic co-scheduling (verified R11: fused dur == bare hist_rank dur).
__global__ __launch_bounds__(256) void gemm1_hist(const float* __restrict__ X,
                                                  const unsigned short* __restrict__ WT,
                                                  unsigned short* __restrict__ G, int n,
                                                  const int* __restrict__ dst,
                                                  int* __restrict__ hist,
                                                  unsigned short* __restrict__ rank, int e) {
    if (blockIdx.x >= GG) {
        int i = (blockIdx.x - GG) * 256 + threadIdx.x;
        if (i < e) rank[i] = (unsigned short)atomicAdd(hist + dst[i], 1);
        return;
    }
    int wave = threadIdx.x >> 6;
    int lane = threadIdx.x & 63;
    int quad = lane >> 4;
    int c = lane & 15;
    int rowbase = blockIdx.x * 64 + wave * 16;

    int arow = rowbase + c;
    if (arow >= n) arow = n - 1;
    const float* ap = X + (size_t)arow * 128 + quad * 8;
    bfx8 a[4];
#pragma unroll
    for (int kc = 0; kc < 4; kc++) {
        float4 u = *(const float4*)(ap + kc * 32);
        float4 v = *(const float4*)(ap + kc * 32 + 4);
        a[kc] = cvt8(u, v);
    }

    f32x4 acc[8];
#pragma unroll
    for (int ct = 0; ct < 8; ct++) acc[ct] = (f32x4){0.f, 0.f, 0.f, 0.f};
#pragma unroll
    for (int ct = 0; ct < 8; ct++) {
        const unsigned short* bp = WT + (size_t)(ct * 16 + c) * 128 + quad * 8;
#pragma unroll
        for (int kc = 0; kc < 4; kc++) {
            bfx8 b = ld8(bp + kc * 32);
            acc[ct] = __builtin_amdgcn_mfma_f32_16x16x32_bf16(a[kc], b, acc[ct], 0, 0, 0);
        }
    }

    int r0 = rowbase + quad * 4;
    bool odd = lane & 1;
#pragma unroll
    for (int ct = 0; ct < 8; ct++) {
        float x0 = acc[ct][0], x1 = acc[ct][1], x2 = acc[ct][2], x3 = acc[ct][3];
        float y0 = __shfl_xor(x0, 1, 64), y1 = __shfl_xor(x1, 1, 64);
        float y2 = __shfl_xor(x2, 1, 64), y3 = __shfl_xor(x3, 1, 64);
        int colp = ct * 16 + (c & ~1);
        if (!odd) {
            if (r0 + 0 < n) *(uint32_t*)(&G[(size_t)(r0 + 0) * 128 + colp]) = pack2bf(x0, y0);
            if (r0 + 1 < n) *(uint32_t*)(&G[(size_t)(r0 + 1) * 128 + colp]) = pack2bf(x1, y1);
        } else {
            if (r0 + 2 < n) *(uint32_t*)(&G[(size_t)(r0 + 2) * 128 + colp]) = pack2bf(y2, x2);
            if (r0 + 3 < n) *(uint32_t*)(&G[(size_t)(r0 + 3) * 128 + colp]) = pack2bf(y3, x3);
        }
    }
}

// ---------- D3: scan1 pieces + bsum + dinv ----------
__global__ void scan_dinv(const int* __restrict__ hist, int* row_ptr, int* bsum,
                          float* dinv, int n) {
    __shared__ int s[256];
    int tid = threadIdx.x;
    int i = blockIdx.x * 256 + tid;
    int v = (i < n) ? hist[i] : 0;
    s[tid] = v;
    __syncthreads();
#pragma unroll
    for (int off = 1; off < 256; off <<= 1) {
        int y = (tid >= off) ? s[tid - off] : 0;
        __syncthreads();
        s[tid] += y;
        __syncthreads();
    }
    if (i < n) {
        row_ptr[i] = s[tid] - v;
        dinv[i] = rsqrtf(1.0f + (float)v);
    }
    if (tid == 255) bsum[blockIdx.x] = s[255];
}

// ---------- D4: bucket with inline LDS scan2; last block publishes boff ----------
__global__ void bucket_k(const int* __restrict__ src, const int* __restrict__ dst,
                         const int* __restrict__ row_ptr, const int* __restrict__ bsum,
                         const unsigned short* __restrict__ rank,
                         unsigned short* __restrict__ csr_src, int* __restrict__ boff_g,
                         int e) {
    __shared__ int s[256];
    __shared__ int bex[256];
    int tid = threadIdx.x;
    int v = (tid < NB) ? bsum[tid] : 0;
    s[tid] = v;
    __syncthreads();
#pragma unroll
    for (int off = 1; off < 256; off <<= 1) {
        int y = (tid >= off) ? s[tid - off] : 0;
        __syncthreads();
        s[tid] += y;
        __syncthreads();
    }
    bex[tid] = s[tid] - v;
    __syncthreads();

    if (blockIdx.x == gridDim.x - 1) {
        if (tid < NB) boff_g[tid] = bex[tid];
        return;
    }
    int i = blockIdx.x * 256 + tid;
    if (i < e) {
        int d = dst[i];
        csr_src[row_ptr[d] + bex[d >> 8] + (int)rank[i]] = (unsigned short)src[i];
    }
}

// ---------- GEMMs for layers 2/3: pre-scale rows by dinv (epilogue) ----------
__global__ __launch_bounds__(256) void gemm128_mfma(const unsigned short* __restrict__ A,
                                                    const unsigned short* __restrict__ WT,
                                                    const float* __restrict__ dinv,
                                                    unsigned short* __restrict__ G, int n) {
    int wave = threadIdx.x >> 6;
    int lane = threadIdx.x & 63;
    int quad = lane >> 4;
    int c = lane & 15;
    int rowbase = blockIdx.x * 64 + wave * 16;

    int arow = rowbase + c;
    if (arow >= n) arow = n - 1;
    const unsigned short* ap = A + (size_t)arow * 128 + quad * 8;
    bfx8 a[4];
#pragma unroll
    for (int kc = 0; kc < 4; kc++) a[kc] = ld8(ap + kc * 32);

    f32x4 acc[8];
#pragma unroll
    for (int ct = 0; ct < 8; ct++) acc[ct] = (f32x4){0.f, 0.f, 0.f, 0.f};
#pragma unroll
    for (int ct = 0; ct < 8; ct++) {
        const unsigned short* bp = WT + (size_t)(ct * 16 + c) * 128 + quad * 8;
#pragma unroll
        for (int kc = 0; kc < 4; kc++) {
            bfx8 b = ld8(bp + kc * 32);
            acc[ct] = __builtin_amdgcn_mfma_f32_16x16x32_bf16(a[kc], b, acc[ct], 0, 0, 0);
        }
    }

    int r0 = rowbase + quad * 4;
    float di[4];
#pragma unroll
    for (int r = 0; r < 4; r++) {
        int rr = r0 + r;
        di[r] = dinv[rr < n ? rr : 0];
    }
    bool odd = lane & 1;
#pragma unroll
    for (int ct = 0; ct < 8; ct++) {
        float x0 = acc[ct][0], x1 = acc[ct][1], x2 = acc[ct][2], x3 = acc[ct][3];
        float y0 = __shfl_xor(x0, 1, 64), y1 = __shfl_xor(x1, 1, 64);
        float y2 = __shfl_xor(x2, 1, 64), y3 = __shfl_xor(x3, 1, 64);
        int colp = ct * 16 + (c & ~1);
        if (!odd) {
            if (r0 + 0 < n) *(uint32_t*)(&G[(size_t)(r0 + 0) * 128 + colp]) = pack2bf(di[0] * x0, di[0] * y0);
            if (r0 + 1 < n) *(uint32_t*)(&G[(size_t)(r0 + 1) * 128 + colp]) = pack2bf(di[1] * x1, di[1] * y1);
        } else {
            if (r0 + 2 < n) *(uint32_t*)(&G[(size_t)(r0 + 2) * 128 + colp]) = pack2bf(di[2] * y2, di[2] * x2);
            if (r0 + 3 < n) *(uint32_t*)(&G[(size_t)(r0 + 3) * 128 + colp]) = pack2bf(di[3] * y3, di[3] * x3);
        }
    }
}

__global__ __launch_bounds__(256) void gemm40_mfma(const unsigned short* __restrict__ A,
                                                   const unsigned short* __restrict__ WT,
                                                   const float* __restrict__ dinv,
                                                   unsigned short* __restrict__ G, int n) {
    int wave = threadIdx.x >> 6;
    int lane = threadIdx.x & 63;
    int quad = lane >> 4;
    int c = lane & 15;
    int rowbase = blockIdx.x * 64 + wave * 16;

    int arow = rowbase + c;
    if (arow >= n) arow = n - 1;
    const unsigned short* ap = A + (size_t)arow * 128 + quad * 8;
    bfx8 a[4];
#pragma unroll
    for (int kc = 0; kc < 4; kc++) a[kc] = ld8(ap + kc * 32);

    f32x4 acc[3];
#pragma unroll
    for (int ct = 0; ct < 3; ct++) acc[ct] = (f32x4){0.f, 0.f, 0.f, 0.f};
#pragma unroll
    for (int ct = 0; ct < 3; ct++) {
        const unsigned short* bp = WT + (size_t)(ct * 16 + c) * 128 + quad * 8;
#pragma unroll
        for (int kc = 0; kc < 4; kc++) {
            bfx8 b = ld8(bp + kc * 32);
            acc[ct] = __builtin_amdgcn_mfma_f32_16x16x32_bf16(a[kc], b, acc[ct], 0, 0, 0);
        }
    }

    int r0 = rowbase + quad * 4;
    float di[4];
#pragma unroll
    for (int r = 0; r < 4; r++) {
        int rr = r0 + r;
        di[r] = dinv[rr < n ? rr : 0];
    }
    bool odd = lane & 1;
#pragma unroll
    for (int ct = 0; ct < 3; ct++) {
        float x0 = acc[ct][0], x1 = acc[ct][1], x2 = acc[ct][2], x3 = acc[ct][3];
        float y0 = __shfl_xor(x0, 1, 64), y1 = __shfl_xor(x1, 1, 64);
        float y2 = __shfl_xor(x2, 1, 64), y3 = __shfl_xor(x3, 1, 64);
        int colp = ct * 16 + (c & ~1);
        if (colp >= 40) continue;
        if (!odd) {
            if (r0 + 0 < n) *(uint32_t*)(&G[(size_t)(r0 + 0) * 40 + colp]) = pack2bf(di[0] * x0, di[0] * y0);
            if (r0 + 1 < n) *(uint32_t*)(&G[(size_t)(r0 + 1) * 40 + colp]) = pack2bf(di[1] * x1, di[1] * y1);
        } else {
            if (r0 + 2 < n) *(uint32_t*)(&G[(size_t)(r0 + 2) * 40 + colp]) = pack2bf(di[2] * y2, di[2] * x2);
            if (r0 + 3 < n) *(uint32_t*)(&G[(size_t)(r0 + 3) * 40 + colp]) = pack2bf(di[3] * y3, di[3] * x3);
        }
    }
}

// ---------- D5: layer-1 aggregate, UNSCALED H1 with per-edge dinv[s] ----------
// 1 wave per node (max TLP — the gather is bandwidth-bound on random rows;
// R12 showed coupling this to GEMM tiles loses 2.5x wave parallelism).
__global__ __launch_bounds__(256) void agg128_l1(const unsigned short* __restrict__ G,
                                                 const int* __restrict__ row_ptr,
                                                 const int* __restrict__ boff,
                                                 const int* __restrict__ hist,
                                                 const unsigned short* __restrict__ csr_src,
                                                 const float* __restrict__ dinv,
                                                 const float* __restrict__ b,
                                                 unsigned short* __restrict__ Y, int n) {
    int node = blockIdx.x * 4 + (threadIdx.x >> 6);
    if (node >= n) return;
    int l = threadIdx.x & 63;
    const uint32_t* Gr = (const uint32_t*)G;

    float dn = dinv[node];
    float2 sf = bfp2f2(Gr[(size_t)node * 64 + l]);
    float2 acc = make_float2(dn * sf.x, dn * sf.y);  // self: dinv[d]*H1[d]
    int p = row_ptr[node] + boff[node >> 8];
    int p1 = p + hist[node];
    for (; p + 7 < p1; p += 8) {
        int s0 = csr_src[p],     s1 = csr_src[p + 1], s2 = csr_src[p + 2], s3 = csr_src[p + 3];
        int s4 = csr_src[p + 4], s5 = csr_src[p + 5], s6 = csr_src[p + 6], s7 = csr_src[p + 7];
        float d0 = dinv[s0], d1 = dinv[s1], d2 = dinv[s2], d3 = dinv[s3];
        float d4 = dinv[s4], d5 = dinv[s5], d6 = dinv[s6], d7 = dinv[s7];
        float2 f0 = bfp2f2(Gr[(size_t)s0 * 64 + l]), f1 = bfp2f2(Gr[(size_t)s1 * 64 + l]);
        float2 f2 = bfp2f2(Gr[(size_t)s2 * 64 + l]), f3 = bfp2f2(Gr[(size_t)s3 * 64 + l]);
        float2 f4 = bfp2f2(Gr[(size_t)s4 * 64 + l]), f5 = bfp2f2(Gr[(size_t)s5 * 64 + l]);
        float2 f6 = bfp2f2(Gr[(size_t)s6 * 64 + l]), f7 = bfp2f2(Gr[(size_t)s7 * 64 + l]);
        acc.x += (fmaf(d0, f0.x, d1 * f1.x) + fmaf(d2, f2.x, d3 * f3.x)) +
                 (fmaf(d4, f4.x, d5 * f5.x) + fmaf(d6, f6.x, d7 * f7.x));
        acc.y += (fmaf(d0, f0.y, d1 * f1.y) + fmaf(d2, f2.y, d3 * f3.y)) +
                 (fmaf(d4, f4.y, d5 * f5.y) + fmaf(d6, f6.y, d7 * f7.y));
    }
    for (; p < p1; ++p) {
        int s = csr_src[p];
        float ds = dinv[s];
        float2 f = bfp2f2(Gr[(size_t)s * 64 + l]);
        acc.x = fmaf(ds, f.x, acc.x);
        acc.y = fmaf(ds, f.y, acc.y);
    }
    float vx = fmaf(dn, acc.x, b[2 * l]);
    float vy = fmaf(dn, acc.y, b[2 * l + 1]);
    ((uint32_t*)Y)[(size_t)node * 64 + l] = pack2bf(vx > 0.f ? vx : 0.f, vy > 0.f ? vy : 0.f);
}

// ---------- D7: layer-2 aggregate (G pre-scaled) ----------
__global__ __launch_bounds__(256) void agg128(const unsigned short* __restrict__ G,
                                              const int* __restrict__ row_ptr,
                                              const int* __restrict__ boff,
                                              const int* __restrict__ hist,
                                              const unsigned short* __restrict__ csr_src,
                                              const float* __restrict__ dinv,
                                              const float* __restrict__ b,
                                              unsigned short* __restrict__ Y, int n) {
    int node = blockIdx.x * 4 + (threadIdx.x >> 6);
    if (node >= n) return;
    int l = threadIdx.x & 63;
    const uint32_t* Gr = (const uint32_t*)G;

    float2 acc = bfp2f2(Gr[(size_t)node * 64 + l]);  // self (pre-scaled)
    int p = row_ptr[node] + boff[node >> 8];
    int p1 = p + hist[node];
    for (; p + 7 < p1; p += 8) {
        int s0 = csr_src[p],     s1 = csr_src[p + 1], s2 = csr_src[p + 2], s3 = csr_src[p + 3];
        int s4 = csr_src[p + 4], s5 = csr_src[p + 5], s6 = csr_src[p + 6], s7 = csr_src[p + 7];
        float2 f0 = bfp2f2(Gr[(size_t)s0 * 64 + l]), f1 = bfp2f2(Gr[(size_t)s1 * 64 + l]);
        float2 f2 = bfp2f2(Gr[(size_t)s2 * 64 + l]), f3 = bfp2f2(Gr[(size_t)s3 * 64 + l]);
        float2 f4 = bfp2f2(Gr[(size_t)s4 * 64 + l]), f5 = bfp2f2(Gr[(size_t)s5 * 64 + l]);
        float2 f6 = bfp2f2(Gr[(size_t)s6 * 64 + l]), f7 = bfp2f2(Gr[(size_t)s7 * 64 + l]);
        acc.x += ((f0.x + f1.x) + (f2.x + f3.x)) + ((f4.x + f5.x) + (f6.x + f7.x));
        acc.y += ((f0.y + f1.y) + (f2.y + f3.y)) + ((f4.y + f5.y) + (f6.y + f7.y));
    }
    for (; p < p1; ++p) {
        float2 f = bfp2f2(Gr[(size_t)csr_src[p] * 64 + l]);
        acc.x += f.x; acc.y += f.y;
    }
    float dn = dinv[node];
    float vx = fmaf(dn, acc.x, b[2 * l]);
    float vy = fmaf(dn, acc.y, b[2 * l + 1]);
    ((uint32_t*)Y)[(size_t)node * 64 + l] = pack2bf(vx > 0.f ? vx : 0.f, vy > 0.f ? vy : 0.f);
}

// ---------- D9: 40-wide aggregate + log_softmax ----------
__global__ __launch_bounds__(256) void agg40_lsm(const unsigned short* __restrict__ G,
                                                 const int* __restrict__ row_ptr,
                                                 const int* __restrict__ boff,
                                                 const int* __restrict__ hist,
                                                 const unsigned short* __restrict__ csr_src,
                                                 const float* __restrict__ dinv,
                                                 const float* __restrict__ b,
                                                 float* __restrict__ Y, int n) {
    int node = blockIdx.x * 4 + (threadIdx.x >> 6);
    if (node >= n) return;
    int lane = threadIdx.x & 63;
    bool act = lane < 40;
    int lc = act ? lane : 0;

    float acc = act ? bf2f(G[(size_t)node * 40 + lane]) : 0.f;
    int p = row_ptr[node] + boff[node >> 8];
    int p1 = p + hist[node];
    for (; p + 3 < p1; p += 4) {
        int s0 = csr_src[p], s1 = csr_src[p + 1], s2 = csr_src[p + 2], s3 = csr_src[p + 3];
        float f0 = bf2f(G[(size_t)s0 * 40 + lc]);
        float f1 = bf2f(G[(size_t)s1 * 40 + lc]);
        float f2 = bf2f(G[(size_t)s2 * 40 + lc]);
        float f3 = bf2f(G[(size_t)s3 * 40 + lc]);
        acc += (f0 + f1) + (f2 + f3);
    }
    for (; p < p1; ++p) acc += bf2f(G[(size_t)csr_src[p] * 40 + lc]);

    float v = act ? fmaf(dinv[node], acc, b[lane]) : -1e30f;
    float m = v;
#pragma unroll
    for (int off = 32; off > 0; off >>= 1) m = fmaxf(m, __shfl_xor(m, off, 64));
    float ex = act ? expf(v - m) : 0.f;
    float s_ = ex;
#pragma unroll
    for (int off = 32; off > 0; off >>= 1) s_ += __shfl_xor(s_, off, 64);
    float ls = logf(s_);
    if (act) Y[(size_t)node * 40 + lane] = v - m - ls;
}

// ---------- launch ----------

extern "C" void kernel_launch(void* const* d_in, const int* in_sizes, int n_in,
                              void* d_out, int out_size, void* d_ws, size_t ws_size,
                              hipStream_t stream) {
    const float* x  = (const float*)d_in[0];
    const int*   ei = (const int*)d_in[1];
    const float* W1 = (const float*)d_in[2];
    const float* b1 = (const float*)d_in[3];
    const float* W2 = (const float*)d_in[4];
    const float* b2 = (const float*)d_in[5];
    const float* W3 = (const float*)d_in[6];
    const float* b3 = (const float*)d_in[7];
    float* out = (float*)d_out;

    const int n = NN, e = NE;
    const int* srcI = ei;
    const int* dstI = ei + e;

    char* ws = (char*)d_ws;
    int*            hist    = (int*)ws;                          // n ints
    int*            row_ptr = (int*)(ws + 200704);               // n ints
    int*            bsum    = (int*)(ws + 401408);               // 256
    int*            boff    = (int*)(ws + 402432);               // 256
    float*          dinv    = (float*)(ws + 403456);             // n fp32
    unsigned short* rank    = (unsigned short*)(ws + 604160);    // E ushort
    unsigned short* csr_src = (unsigned short*)(ws + 2204160);   // E ushort
    unsigned short* WT1     = (unsigned short*)(ws + 3804160);   // 128x128 bf16
    unsigned short* WT2     = (unsigned short*)(ws + 3836928);
    unsigned short* WT3     = (unsigned short*)(ws + 3869696);   // 48x128 bf16
    unsigned short* bufG    = (unsigned short*)(ws + 3881984);   // n*128 bf16
    unsigned short* bufA    = (unsigned short*)(ws + 16681984);  // n*128 bf16

    // D1: W transposes + zero hist
    prep<<<152 + NB, 256, 0, stream>>>(W1, W2, W3, WT1, WT2, WT3, hist);
    // D2: layer-1 GEMM (unscaled) ∪ histogram+ranks
    gemm1_hist<<<GG + EB, 256, 0, stream>>>(x, WT1, bufG, n, dstI, hist, rank, e);
    // D3: scan pieces + dinv
    scan_dinv<<<NB, 256, 0, stream>>>(hist, row_ptr, bsum, dinv, n);
    // D4: bucket (inline scan2) + boff publish
    bucket_k<<<EB + 1, 256, 0, stream>>>(srcI, dstI, row_ptr, bsum, rank, csr_src, boff, e);
    // D5: aggregate layer 1 (per-edge dinv)
    agg128_l1<<<(n + 3) / 4, 256, 0, stream>>>(bufG, row_ptr, boff, hist, csr_src, dinv, b1, bufA, n);
    // D6: layer-2 GEMM (pre-scaled)
    gemm128_mfma<<<GG, 256, 0, stream>>>(bufA, WT2, dinv, bufG, n);
    // D7: aggregate layer 2
    agg128<<<(n + 3) / 4, 256, 0, stream>>>(bufG, row_ptr, boff, hist, csr_src, dinv, b2, bufA, n);
    // D8: layer-3 GEMM (40-wide, pre-scaled)
    gemm40_mfma<<<GG, 256, 0, stream>>>(bufA, WT3, dinv, bufG, n);
    // D9: aggregate + log_softmax -> out
    agg40_lsm<<<(n + 3) / 4, 256, 0, stream>>>(bufG, row_ptr, boff, hist, csr_src, dinv, b3, out, n);
}